// Round 4
// baseline (611.283 us; speedup 1.0000x reference)
//
#include <hip/hip_runtime.h>

// Problem constants (B, T, IN, H, OUT) = (256, 128, 128, 256, 128)
// External tensors f32; internal MFMA in bf16 with f32 accumulate; gx
// workspace bf16 PRE-SCALED by log2e (r,z gates) / 2*log2e (n gate) so the
// gate math needs no multiplies before exp2.
//
// Round-9: R3 showed phase serialization: step = 3675 cyc vs 1862-cyc MFMA
// floor (384 MFMA x 4.85 cyc/CU), MfmaUtil(active) 43%. Fixes:
//  (a) eager-hoist all 8 ds_read_b128 to step top (independent of MFMAs;
//      LDS stream overlaps MFMA issue instead of JIT-serializing via lgkmcnt)
//  (b) chain-major MFMA order R8->Z8->N8: accR/accZ retire early; r/z
//      sigmoids run on VALU/trans pipes while the N chain drains the matrix
//      pipe. Only the nv->tanh->hv tail stays serial. setprio(1) on MFMAs.
//  (c) cost: 8 frags live across chains = +~30 VGPR (64->~96; no spill at
//      4 waves/SIMD with 512-reg cap). WRITE_SIZE is the spill tripwire.
//  (d) gx_gemm A-load: 4-lane groups now read 64B contiguous (was 16B
//      granules at 128B stride) for the cold-HBM x read.
#define B_   256
#define T_   128
#define IN_  128
#define H_   256
#define H3_  768
#define OUT_ 128

#define L2E  1.4426950408889634f

typedef unsigned short u16;
typedef u16   u16x2  __attribute__((ext_vector_type(2)));
typedef u16   u16x4  __attribute__((ext_vector_type(4)));
typedef u16   u16x8  __attribute__((ext_vector_type(8)));
typedef __bf16 bf16x8 __attribute__((ext_vector_type(8)));
typedef float f32x2  __attribute__((ext_vector_type(2)));
typedef float f32x4  __attribute__((ext_vector_type(4)));

__device__ __forceinline__ float bf2f(u16 u) {
  unsigned int v = ((unsigned int)u) << 16;
  return __builtin_bit_cast(float, v);
}
__device__ __forceinline__ u16 f2bf(float f) {        // RNE (off hot path)
  unsigned int u = __builtin_bit_cast(unsigned int, f);
  u += 0x7fffu + ((u >> 16) & 1u);
  return (u16)(u >> 16);
}
__device__ __forceinline__ u16 f2bf_fast(float f) {   // round-half-up
  unsigned int u = __builtin_bit_cast(unsigned int, f);
  return (u16)((u + 0x8000u) >> 16);
}
__device__ __forceinline__ f32x4 mfma16(bf16x8 a, bf16x8 b, f32x4 c) {
  return __builtin_amdgcn_mfma_f32_16x16x32_bf16(a, b, c, 0, 0, 0);
}
__device__ __forceinline__ float exp2f_(float x) {
#if __has_builtin(__builtin_amdgcn_exp2f)
  return __builtin_amdgcn_exp2f(x);
#else
  return __builtin_exp2f(x);
#endif
}
__device__ __forceinline__ float rcp_(float x) { return __builtin_amdgcn_rcpf(x); }

// constant-index select of acc element e (avoids runtime vector indexing)
__device__ __forceinline__ float pick4(f32x4 v, int e) {
  float r = v[0];
  r = (e == 1) ? v[1] : r;
  r = (e == 2) ? v[2] : r;
  r = (e == 3) ? v[3] : r;
  return r;
}

// ---------------------------------------------------------------------------
// Kernel 1 (fused prep):
//  blocks [0,384):  Wx (f32, 128x768) -> WxT (bf16, 768x128), unscaled
//  blocks [384,480): Wh (f32, 256x768) -> whp: bf16 fragments PRE-PACKED in
//    the exact per-thread order cru_scan consumes (layout is block-invariant)
__global__ __launch_bounds__(256) void prep(const float* __restrict__ Wx,
                                            const float* __restrict__ Wh,
                                            u16* __restrict__ WxT,
                                            u16* __restrict__ whp) {
  const int bid = blockIdx.x;
  if (bid < 384) {
    int o = bid * 256 + threadIdx.x;            // 0..98303
    int n = o >> 7, k = o & 127;
    WxT[o] = f2bf(Wx[(size_t)k * H3_ + n]);
  } else {
    int o8 = (bid - 384) * 256 + threadIdx.x;   // 0..24575 (one u16x8 each)
    int kk = o8 & 7;
    int g  = (o8 >> 3) % 3;
    int tp = o8 / 24;                           // scan-kernel tid, 0..1023
    int l  = tp & 63, w = tp >> 6;
    int n  = g * 256 + w * 16 + (l & 15);
    int rowb = kk * 32 + (((l >> 4) & 3) << 3);
    float sgw = (g < 2) ? L2E : (2.f * L2E);
    u16x8 v;
    #pragma unroll
    for (int j = 0; j < 8; ++j)
      v[j] = f2bf(Wh[(size_t)(rowb + j) * H3_ + n] * sgw);
    *(u16x8*)(whp + (size_t)o8 * 8) = v;
  }
}

// ---------------------------------------------------------------------------
// Kernel 2: gx[t*B+b][n] = bf16( (x[b,t,:]@Wx[:,n] + bx[n] + (n<512?bh[n]:0)) * sc )
// sc = L2E for r/z gates (n<512), 2*L2E for n gate. M=32768, N=768, K=128.
// Tile 128(M) x 192(N), 512 threads (8 waves as 2Mx4N). C staged via LDS.
__global__ __launch_bounds__(512) void gx_gemm(const float* __restrict__ x,
                                               const u16* __restrict__ WxT,
                                               const float* __restrict__ bx,
                                               const float* __restrict__ bh,
                                               u16* __restrict__ gxw) {
  __shared__ __align__(16) char smem[(128 * 136 + 192 * 136) * 2];  // 87 KB
  u16 (*As)[136] = (u16(*)[136])smem;
  u16 (*Bs)[136] = (u16(*)[136])(smem + 128 * 136 * 2);
  u16 (*St)[204] = (u16(*)[204])smem;       // aliases As/Bs after 2nd barrier

  const int mt = blockIdx.x;                  // 0..255
  const int n0 = blockIdx.y * 192;            // 0,192,384,576
  const int m0 = mt * 128;
  const int t  = mt >> 1;
  const int brow0 = (mt & 1) * 128;
  const int tid = threadIdx.x;
  const int w = tid >> 6, lane = tid & 63, quad = lane >> 4, r = lane & 15;
  const int wm = w >> 2, wn = w & 3;          // 2 x 4 wave grid

  {  // A tile: 128 rows x 128 cols, f32 -> bf16; 4-lane groups read 64B
     // contiguous per c4 (coalesced cold-HBM x read)
    int row = tid >> 2;
    int colc = (tid & 3) * 4;
    const float* s = x + ((size_t)(brow0 + row) * T_ + t) * IN_ + colc;
    #pragma unroll
    for (int c4 = 0; c4 < 8; ++c4) {
      f32x4 v = *(const f32x4*)(s + c4 * 16);
      u16x4 b;
      b[0] = f2bf(v[0]); b[1] = f2bf(v[1]); b[2] = f2bf(v[2]); b[3] = f2bf(v[3]);
      *(u16x4*)&As[row][colc + c4 * 16] = b;
    }
  }
  {  // B tile [n][k] from WxT: 192 x 128 u16
    #pragma unroll
    for (int i = 0; i < 6; ++i) {
      int idx = tid + i * 512;                // 0..3071
      int row = idx >> 4, col8 = (idx & 15) * 8;
      *(u16x8*)&Bs[row][col8] = *(const u16x8*)(WxT + (size_t)(n0 + row) * IN_ + col8);
    }
  }
  __syncthreads();

  f32x4 acc[4][3];
  #pragma unroll
  for (int i = 0; i < 4; ++i)
    #pragma unroll
    for (int j = 0; j < 3; ++j)
      acc[i][j] = (f32x4){0.f, 0.f, 0.f, 0.f};

  #pragma unroll
  for (int kk = 0; kk < 4; ++kk) {
    bf16x8 a[4];
    #pragma unroll
    for (int m2 = 0; m2 < 4; ++m2)
      a[m2] = *(const bf16x8*)&As[wm * 64 + m2 * 16 + r][kk * 32 + quad * 8];
    #pragma unroll
    for (int n2 = 0; n2 < 3; ++n2) {
      bf16x8 b = *(const bf16x8*)&Bs[wn * 48 + n2 * 16 + r][kk * 32 + quad * 8];
      #pragma unroll
      for (int m2 = 0; m2 < 4; ++m2)
        acc[m2][n2] = mfma16(a[m2], b, acc[m2][n2]);
    }
  }

  __syncthreads();   // all LDS reads done; safe to alias As/Bs as St

  #pragma unroll
  for (int m2 = 0; m2 < 4; ++m2)
    #pragma unroll
    for (int n2 = 0; n2 < 3; ++n2) {
      int nl = wn * 48 + n2 * 16 + r;                  // local col (C col = lane&15)
      int n  = n0 + nl;
      float sc = (n < 512) ? L2E : (2.f * L2E);
      float bias = bx[n] + (n < 512 ? bh[n] : 0.f);
      #pragma unroll
      for (int e = 0; e < 4; ++e) {                    // C row = quad*4 + e
        int mrow = wm * 64 + m2 * 16 + quad * 4 + e;
        St[mrow][nl] = f2bf((acc[m2][n2][e] + bias) * sc);
      }
    }
  __syncthreads();

  #pragma unroll
  for (int i = 0; i < 6; ++i) {                        // coalesced 16B stores
    int idx = tid + i * 512;                           // 0..3071
    int row = idx / 24, c8 = (idx % 24) * 8;
    *(u16x8*)(gxw + (size_t)(m0 + row) * H3_ + n0 + c8) = *(const u16x8*)&St[row][c8];
  }
}

// ---------------------------------------------------------------------------
// Kernel 3: the scan. 192 blocks x 1024 threads (16 waves), 4 batch rows per
// block. Per step per thread: 3 scalar gx loads -> 8 EAGER ds_read_b128 ->
// chain-major 24 MFMA (R8,Z8,N8, setprio-wrapped) -> r/z sigmoids overlap
// the N-chain drain -> short tanh tail -> 1 ds_write_b16 -> one barrier.
// Fragment file: 96 regs (AGPR-resident), pre-packed in whp.
__global__ __launch_bounds__(1024)
void cru_scan(const float* __restrict__ hid,
              const u16*  __restrict__ whp,
              const float* __restrict__ bh,
              const u16*  __restrict__ gx,
              float* __restrict__ hT) {
  __shared__ __align__(16) u16 h_bf[2][4][288];   // double buffer, 4.6 KB

  const int bid = blockIdx.x;           // 192 blocks
  const int c   = bid >> 6;             // component 0..2
  const int b0  = (bid & 63) << 2;      // batch row group of 4
  const int tid = threadIdx.x;
  const int lane = tid & 63, quad = lane >> 4, m = lane & 15;
  const int w  = tid >> 6;              // wave 0..15
  const int bb = m & 3;                 // batch row within group
  const int e  = m >> 2;                // kept accumulator element
  const int hcol = w * 16 + quad * 4 + e;   // owned n-col 0..255

  // --- one-time fragment load: 384 B contiguous per thread, coalesced ---
  bf16x8 bfr[3][8];
  {
    const u16* wp = whp + (size_t)tid * 192;
    #pragma unroll
    for (int g = 0; g < 3; ++g)
      #pragma unroll
      for (int kk = 0; kk < 8; ++kk)
        bfr[g][kk] = *(const bf16x8*)(wp + g * 64 + kk * 8);
  }

  // --- this lane's h element: h[bb][hcol] ---
  const size_t hrow = (size_t)(c * 256 + b0 + bb) * 256 + hcol;
  float hx = hid[hrow];
  h_bf[0][bb][hcol] = f2bf(hx);
  const float bn0 = bh[512 + hcol] * (2.f * L2E);

  const u16* gxp = gx + (size_t)(b0 + bb) * H3_ + hcol;
  const int rbase = bb * 288 + quad * 8;       // B-frag read base (u16 units)

  __syncthreads();

  #pragma unroll 2
  for (int t = 0; t < T_; ++t) {
    const int sel = t & 1;
    // A) issue this step's gx loads; consumed after the MFMA phase
    const u16* src = gxp + (size_t)t * (B_ * H3_);
    u16 xr = src[0];
    u16 xz = src[256];
    u16 xn = src[512];

    // B) eager B-frag reads: all 8 issued before any MFMA (LDS stream
    //    overlaps MFMA issue; reads depend only on the barrier)
    const u16* hb = &h_bf[sel][0][0];
    bf16x8 f0 = *(const bf16x8*)(hb + rbase);
    bf16x8 f1 = *(const bf16x8*)(hb + rbase + 32);
    bf16x8 f2 = *(const bf16x8*)(hb + rbase + 64);
    bf16x8 f3 = *(const bf16x8*)(hb + rbase + 96);
    bf16x8 f4 = *(const bf16x8*)(hb + rbase + 128);
    bf16x8 f5 = *(const bf16x8*)(hb + rbase + 160);
    bf16x8 f6 = *(const bf16x8*)(hb + rbase + 192);
    bf16x8 f7 = *(const bf16x8*)(hb + rbase + 224);

    // C) chain-major MFMA: R and Z chains complete early so their sigmoids
    //    overlap the N chain's drain of the matrix pipe.
    __builtin_amdgcn_s_setprio(1);
    f32x4 accR = {0.f, 0.f, 0.f, 0.f};
    accR = mfma16(bfr[0][0], f0, accR);
    accR = mfma16(bfr[0][1], f1, accR);
    accR = mfma16(bfr[0][2], f2, accR);
    accR = mfma16(bfr[0][3], f3, accR);
    accR = mfma16(bfr[0][4], f4, accR);
    accR = mfma16(bfr[0][5], f5, accR);
    accR = mfma16(bfr[0][6], f6, accR);
    accR = mfma16(bfr[0][7], f7, accR);
    f32x4 accZ = {0.f, 0.f, 0.f, 0.f};
    accZ = mfma16(bfr[1][0], f0, accZ);
    accZ = mfma16(bfr[1][1], f1, accZ);
    accZ = mfma16(bfr[1][2], f2, accZ);
    accZ = mfma16(bfr[1][3], f3, accZ);
    accZ = mfma16(bfr[1][4], f4, accZ);
    accZ = mfma16(bfr[1][5], f5, accZ);
    accZ = mfma16(bfr[1][6], f6, accZ);
    accZ = mfma16(bfr[1][7], f7, accZ);
    f32x4 accN = {0.f, 0.f, 0.f, 0.f};
    accN = mfma16(bfr[2][0], f0, accN);
    accN = mfma16(bfr[2][1], f1, accN);
    accN = mfma16(bfr[2][2], f2, accN);
    accN = mfma16(bfr[2][3], f3, accN);
    accN = mfma16(bfr[2][4], f4, accN);
    accN = mfma16(bfr[2][5], f5, accN);
    accN = mfma16(bfr[2][6], f6, accN);
    accN = mfma16(bfr[2][7], f7, accN);
    __builtin_amdgcn_s_setprio(0);

    // D) r/z sigmoids: read only accR/accZ (retired ~16 MFMA-issues early)
    float gR = pick4(accR, e), gZ = pick4(accZ, e);
    float sr = rcp_(1.f + exp2f_(-(bf2f(xr) + gR)));       // sigmoid
    float sz = rcp_(1.f + exp2f_(-(bf2f(xz) + gZ)));

    // E) short serial tail: tanh + GRU update
    float gN = pick4(accN, e);
    float nv = bf2f(xn) + sr * (gN + bn0);                 // 2*L2E-scaled
    float nn = fmaf(2.f, rcp_(1.f + exp2f_(-nv)), -1.f);   // tanh, inf-safe
    float hv = nn + sz * (hx - nn);
    hx = hv;
    h_bf[sel ^ 1][bb][hcol] = f2bf_fast(hv);
    __syncthreads();   // h_bf[sel^1] ready; orders next-step reads of sel
  }

  hT[hrow] = hx;
}

// ---------------------------------------------------------------------------
// Kernel 4: out[b] = elu(sum_c hT[c,b,:] @ Wf + bf); feature[c,:] = mean_b hT
__global__ __launch_bounds__(128) void finalize(const float* __restrict__ hT,
                                                const float* __restrict__ Wf,
                                                const float* __restrict__ bfv,
                                                float* __restrict__ out) {
  __shared__ float hsum[256];
  const int bid = blockIdx.x, tid = threadIdx.x;
  if (bid < 256) {
    const int b = bid;
    for (int k = tid; k < 256; k += 128)
      hsum[k] = hT[((size_t)(0 * 256 + b)) * 256 + k]
              + hT[((size_t)(1 * 256 + b)) * 256 + k]
              + hT[((size_t)(2 * 256 + b)) * 256 + k];
    __syncthreads();
    float acc = bfv[tid];
    #pragma unroll 8
    for (int k = 0; k < 256; ++k)
      acc = fmaf(hsum[k], Wf[(size_t)k * OUT_ + tid], acc);
    float rv = acc > 0.f ? acc : (__expf(acc) - 1.f);
    out[b * OUT_ + tid] = rv;
  } else {
    const int idx = bid - 256;                 // 0..5
    const int c = idx >> 1, j = ((idx & 1) << 7) + tid;
    float sum = 0.f;
    #pragma unroll 4
    for (int b = 0; b < 256; ++b)
      sum += hT[((size_t)(c * 256 + b)) * 256 + j];
    out[B_ * OUT_ + c * 256 + j] = sum * (1.f / 256.f);
  }
}

// ---------------------------------------------------------------------------
extern "C" void kernel_launch(void* const* d_in, const int* in_sizes, int n_in,
                              void* d_out, int out_size, void* d_ws, size_t ws_size,
                              hipStream_t stream) {
  const float* x   = (const float*)d_in[0];
  const float* hid = (const float*)d_in[1];
  const float* Wx  = (const float*)d_in[2];
  const float* bx  = (const float*)d_in[3];
  const float* Wh  = (const float*)d_in[4];
  const float* bh  = (const float*)d_in[5];
  const float* Wf  = (const float*)d_in[6];
  const float* bf_ = (const float*)d_in[7];
  float* out = (float*)d_out;

  char* ws = (char*)d_ws;
  u16* WxT   = (u16*)ws;                                   // 768*128 bf16 = 192 KiB
  u16* gxw   = (u16*)(ws + (1 << 18));                     // 128*256*768 bf16 = 48 MiB
  float* hTw = (float*)(ws + (1 << 18) + (size_t)T_ * B_ * H3_ * 2);  // 3*256*256 f32
  u16* whp   = (u16*)(ws + (1 << 18) + (size_t)T_ * B_ * H3_ * 2
                         + (size_t)3 * 256 * 256 * 4);     // 256*768 bf16 = 384 KiB

  prep<<<480, 256, 0, stream>>>(Wx, Wh, WxT, whp);
  gx_gemm<<<dim3(256, 4), 512, 0, stream>>>(x, WxT, bx, bh, gxw);
  cru_scan<<<192, 1024, 0, stream>>>(hid, whp, bh, gxw, hTw);
  finalize<<<262, 128, 0, stream>>>(hTw, Wf, bf_, out);
}

// Round 6
// 256.697 us; speedup vs baseline: 2.3813x; 2.3813x over previous
//
#include <hip/hip_runtime.h>

// Problem constants (B, T, IN, H, OUT) = (256, 128, 128, 256, 128)
// External tensors f32; gx workspace bf16 PRE-SCALED by log2e / 2*log2e.
//
// Round-11: R5's int8 scan failed with absmax 8.05 = saturated-gates
// signature. Root cause: dequant constants missed the /127 from
// h_q = rint(h*127):  acc = (127/sW)*gh  =>  gh = acc * sW/127.
// Fix: dqX = sW[n] * gatefac / 127. Everything else unchanged from R5
// (single-variable isolation: pass => int8 path + byte<->k map validated).
//
// Recap of the int8 design (R5): 1024-thr blocks cap VGPR at 128/wave; bf16
// frag file (96) left no scheduling headroom (R2/R4 spilled). INT8 via
// mfma_i32_16x16x64_i8 (K=64): frag file 48 VGPRs, 12 MFMA/step/wave
// (per-CU floor ~980 cyc vs bf16 1862), 4 eager ds_read_b128, chain-major
// R4,Z4,N4 so r/z sigmoids overlap the N-chain drain.
// Layout safety: A (prep pack) and B (h8 in LDS) use the SAME byte<->k map
// (k = kk*64 + quad*16 + j); any HW k-permutation cancels in the dot product.
// C/D layout dtype-independent => lane ownership identical to R3.
#define B_   256
#define T_   128
#define IN_  128
#define H_   256
#define H3_  768
#define OUT_ 128

#define L2E  1.4426950408889634f

typedef unsigned short u16;
typedef u16   u16x4  __attribute__((ext_vector_type(4)));
typedef u16   u16x8  __attribute__((ext_vector_type(8)));
typedef __bf16 bf16x8 __attribute__((ext_vector_type(8)));
typedef float f32x4  __attribute__((ext_vector_type(4)));
typedef int   i32x4  __attribute__((ext_vector_type(4)));
typedef signed char c8x8 __attribute__((ext_vector_type(8)));

__device__ __forceinline__ float bf2f(u16 u) {
  unsigned int v = ((unsigned int)u) << 16;
  return __builtin_bit_cast(float, v);
}
__device__ __forceinline__ u16 f2bf(float f) {        // RNE (off hot path)
  unsigned int u = __builtin_bit_cast(unsigned int, f);
  u += 0x7fffu + ((u >> 16) & 1u);
  return (u16)(u >> 16);
}
__device__ __forceinline__ f32x4 mfma16(bf16x8 a, bf16x8 b, f32x4 c) {
  return __builtin_amdgcn_mfma_f32_16x16x32_bf16(a, b, c, 0, 0, 0);
}
__device__ __forceinline__ i32x4 mfma8(i32x4 a, i32x4 b, i32x4 c) {
  return __builtin_amdgcn_mfma_i32_16x16x64_i8(a, b, c, 0, 0, 0);
}
__device__ __forceinline__ float exp2f_(float x) {
#if __has_builtin(__builtin_amdgcn_exp2f)
  return __builtin_amdgcn_exp2f(x);
#else
  return __builtin_exp2f(x);
#endif
}
__device__ __forceinline__ float rcp_(float x) { return __builtin_amdgcn_rcpf(x); }

__device__ __forceinline__ int pick4i(i32x4 v, int e) {
  int r = v[0];
  r = (e == 1) ? v[1] : r;
  r = (e == 2) ? v[2] : r;
  r = (e == 3) ? v[3] : r;
  return r;
}

// ---------------------------------------------------------------------------
// Kernel 0: per-column scales sW[n] = max_k |Wh[k,n]| / 127
__global__ __launch_bounds__(256) void wh_scales(const float* __restrict__ Wh,
                                                 float* __restrict__ sw) {
  int n = blockIdx.x * 256 + threadIdx.x;      // 0..767
  float m = 1e-30f;
  #pragma unroll 4
  for (int k = 0; k < 256; ++k)
    m = fmaxf(m, fabsf(Wh[(size_t)k * H3_ + n]));
  sw[n] = m * (1.f / 127.f);
}

// ---------------------------------------------------------------------------
// Kernel 1 (fused prep):
//  blocks [0,384):  Wx (f32, 128x768) -> WxT (bf16, 768x128), unscaled
//  blocks [384,480): Wh -> whp8: INT8 fragments pre-packed per scan thread:
//    whp8[tid*192 + g*64 + kk*16 + (j8*8+j)] =
//      rint(Wh[kk*64 + quad*16 + j8*8 + j][n] / sW[n]),
//    n = g*256 + (tid>>6)*16 + (tid&15), quad = (tid&63)>>4.
__global__ __launch_bounds__(256) void prep(const float* __restrict__ Wx,
                                            const float* __restrict__ Wh,
                                            const float* __restrict__ sw,
                                            u16* __restrict__ WxT,
                                            signed char* __restrict__ whp8) {
  const int bid = blockIdx.x;
  if (bid < 384) {
    int o = bid * 256 + threadIdx.x;            // 0..98303
    int n = o >> 7, k = o & 127;
    WxT[o] = f2bf(Wx[(size_t)k * H3_ + n]);
  } else {
    int o8 = (bid - 384) * 256 + threadIdx.x;   // 0..24575 (8 bytes each)
    int j8 = o8 & 1;
    int kk = (o8 >> 1) & 3;
    int g  = (o8 >> 3) % 3;
    int tp = o8 / 24;                           // scan-kernel tid, 0..1023
    int l  = tp & 63, w = tp >> 6;
    int n  = g * 256 + w * 16 + (l & 15);
    int kbase = kk * 64 + ((l >> 4) & 3) * 16 + j8 * 8;
    float rs = rcp_(sw[n]);                     // 127 / max_k|Wh[:,n]|
    c8x8 v;
    #pragma unroll
    for (int j = 0; j < 8; ++j) {
      float q = __builtin_rintf(Wh[(size_t)(kbase + j) * H3_ + n] * rs);
      v[j] = (signed char)(int)q;
    }
    *(c8x8*)(whp8 + (size_t)o8 * 8) = v;
  }
}

// ---------------------------------------------------------------------------
// Kernel 2: gx[t*B+b][n] = bf16( (x[b,t,:]@Wx[:,n] + bx[n] + (n<512?bh[n]:0)) * sc )
// sc = L2E for r/z gates (n<512), 2*L2E for n gate. M=32768, N=768, K=128.
// Tile 128(M) x 192(N), 512 threads (8 waves as 2Mx4N). C staged via LDS.
__global__ __launch_bounds__(512) void gx_gemm(const float* __restrict__ x,
                                               const u16* __restrict__ WxT,
                                               const float* __restrict__ bx,
                                               const float* __restrict__ bh,
                                               u16* __restrict__ gxw) {
  __shared__ __align__(16) char smem[(128 * 136 + 192 * 136) * 2];  // 87 KB
  u16 (*As)[136] = (u16(*)[136])smem;
  u16 (*Bs)[136] = (u16(*)[136])(smem + 128 * 136 * 2);
  u16 (*St)[204] = (u16(*)[204])smem;       // aliases As/Bs after 2nd barrier

  const int mt = blockIdx.x;                  // 0..255
  const int n0 = blockIdx.y * 192;            // 0,192,384,576
  const int m0 = mt * 128;
  const int t  = mt >> 1;
  const int brow0 = (mt & 1) * 128;
  const int tid = threadIdx.x;
  const int w = tid >> 6, lane = tid & 63, quad = lane >> 4, r = lane & 15;
  const int wm = w >> 2, wn = w & 3;          // 2 x 4 wave grid

  {  // A tile: 128 rows x 128 cols, f32 -> bf16; 4-lane groups read 64B
    int row = tid >> 2;
    int colc = (tid & 3) * 4;
    const float* s = x + ((size_t)(brow0 + row) * T_ + t) * IN_ + colc;
    #pragma unroll
    for (int c4 = 0; c4 < 8; ++c4) {
      f32x4 v = *(const f32x4*)(s + c4 * 16);
      u16x4 b;
      b[0] = f2bf(v[0]); b[1] = f2bf(v[1]); b[2] = f2bf(v[2]); b[3] = f2bf(v[3]);
      *(u16x4*)&As[row][colc + c4 * 16] = b;
    }
  }
  {  // B tile [n][k] from WxT: 192 x 128 u16
    #pragma unroll
    for (int i = 0; i < 6; ++i) {
      int idx = tid + i * 512;                // 0..3071
      int row = idx >> 4, col8 = (idx & 15) * 8;
      *(u16x8*)&Bs[row][col8] = *(const u16x8*)(WxT + (size_t)(n0 + row) * IN_ + col8);
    }
  }
  __syncthreads();

  f32x4 acc[4][3];
  #pragma unroll
  for (int i = 0; i < 4; ++i)
    #pragma unroll
    for (int j = 0; j < 3; ++j)
      acc[i][j] = (f32x4){0.f, 0.f, 0.f, 0.f};

  #pragma unroll
  for (int kk = 0; kk < 4; ++kk) {
    bf16x8 a[4];
    #pragma unroll
    for (int m2 = 0; m2 < 4; ++m2)
      a[m2] = *(const bf16x8*)&As[wm * 64 + m2 * 16 + r][kk * 32 + quad * 8];
    #pragma unroll
    for (int n2 = 0; n2 < 3; ++n2) {
      bf16x8 b = *(const bf16x8*)&Bs[wn * 48 + n2 * 16 + r][kk * 32 + quad * 8];
      #pragma unroll
      for (int m2 = 0; m2 < 4; ++m2)
        acc[m2][n2] = mfma16(a[m2], b, acc[m2][n2]);
    }
  }

  __syncthreads();   // all LDS reads done; safe to alias As/Bs as St

  #pragma unroll
  for (int m2 = 0; m2 < 4; ++m2)
    #pragma unroll
    for (int n2 = 0; n2 < 3; ++n2) {
      int nl = wn * 48 + n2 * 16 + r;                  // local col (C col = lane&15)
      int n  = n0 + nl;
      float sc = (n < 512) ? L2E : (2.f * L2E);
      float bias = bx[n] + (n < 512 ? bh[n] : 0.f);
      #pragma unroll
      for (int e = 0; e < 4; ++e) {                    // C row = quad*4 + e
        int mrow = wm * 64 + m2 * 16 + quad * 4 + e;
        St[mrow][nl] = f2bf((acc[m2][n2][e] + bias) * sc);
      }
    }
  __syncthreads();

  #pragma unroll
  for (int i = 0; i < 6; ++i) {                        // coalesced 16B stores
    int idx = tid + i * 512;                           // 0..3071
    int row = idx / 24, c8 = (idx % 24) * 8;
    *(u16x8*)(gxw + (size_t)(m0 + row) * H3_ + n0 + c8) = *(const u16x8*)&St[row][c8];
  }
}

// ---------------------------------------------------------------------------
// Kernel 3: the scan, INT8. 192 blocks x 1024 threads, 4 batch rows/block.
// Per step per thread: 3 scalar gx loads -> 4 eager ds_read_b128 (h int8,
// 2-way-aliased banks = free) -> 12 MFMA i32_16x16x64_i8 as R4,Z4,N4 chains
// (r/z sigmoids overlap N drain) -> dequant (sW/127 folded) -> rint(h*127)
// -> ds_write_b8 -> one barrier. Registers: 48 frag + 16 f + 12 acc + ~24
// misc = ~100 < 128 cap (WRITE_SIZE is the spill tripwire).
__global__ __launch_bounds__(1024)
void cru_scan(const float* __restrict__ hid,
              const signed char* __restrict__ whp8,
              const float* __restrict__ sw,
              const float* __restrict__ bh,
              const u16*  __restrict__ gx,
              float* __restrict__ hT) {
  __shared__ __align__(16) signed char h8[2][4][288];   // double buffer, 2.3 KB

  const int bid = blockIdx.x;           // 192 blocks
  const int c   = bid >> 6;             // component 0..2
  const int b0  = (bid & 63) << 2;      // batch row group of 4
  const int tid = threadIdx.x;
  const int lane = tid & 63, quad = lane >> 4, m = lane & 15;
  const int w  = tid >> 6;              // wave 0..15
  const int bb = m & 3;                 // batch row within group
  const int e  = m >> 2;                // kept accumulator element
  const int hcol = w * 16 + quad * 4 + e;   // owned n-col 0..255

  // --- one-time fragment load: 192 B contiguous per thread, coalesced ---
  i32x4 bfr[3][4];
  {
    const signed char* wp = whp8 + (size_t)tid * 192;
    #pragma unroll
    for (int g = 0; g < 3; ++g)
      #pragma unroll
      for (int kk = 0; kk < 4; ++kk)
        bfr[g][kk] = *(const i32x4*)(wp + g * 64 + kk * 16);
  }

  // --- dequant constants: gh = acc * sW/127, then gate prescale ---
  const float dqR = sw[hcol]       * (L2E / 127.f);
  const float dqZ = sw[256 + hcol] * (L2E / 127.f);
  const float dqN = sw[512 + hcol] * (2.f * L2E / 127.f);

  // --- this lane's h element: h[bb][hcol] ---
  const size_t hrow = (size_t)(c * 256 + b0 + bb) * 256 + hcol;
  float hx = hid[hrow];
  h8[0][bb][hcol] = (signed char)(int)__builtin_rintf(fminf(fmaxf(hx, -1.f), 1.f) * 127.f);
  const float bn0 = bh[512 + hcol] * (2.f * L2E);

  const u16* gxp = gx + (size_t)(b0 + bb) * H3_ + hcol;
  const int rbase = bb * 288 + quad * 16;      // B-frag read base (bytes)

  __syncthreads();

  #pragma unroll 2
  for (int t = 0; t < T_; ++t) {
    const int sel = t & 1;
    // A) issue this step's gx loads; consumed in the epilogue
    const u16* src = gxp + (size_t)t * (B_ * H3_);
    u16 xr = src[0];
    u16 xz = src[256];
    u16 xn = src[512];

    // B) eager B-frag reads (4 x ds_read_b128, 16 distinct addrs, 4-way
    //    same-address broadcast, 2-way bank aliasing = free)
    const signed char* hb = &h8[sel][0][0];
    i32x4 f0 = *(const i32x4*)(hb + rbase);
    i32x4 f1 = *(const i32x4*)(hb + rbase + 64);
    i32x4 f2 = *(const i32x4*)(hb + rbase + 128);
    i32x4 f3 = *(const i32x4*)(hb + rbase + 192);

    // C) chain-ordered MFMA: R,Z retire early; their sigmoids overlap N
    __builtin_amdgcn_s_setprio(1);
    i32x4 accR = {0, 0, 0, 0};
    accR = mfma8(bfr[0][0], f0, accR);
    accR = mfma8(bfr[0][1], f1, accR);
    accR = mfma8(bfr[0][2], f2, accR);
    accR = mfma8(bfr[0][3], f3, accR);
    i32x4 accZ = {0, 0, 0, 0};
    accZ = mfma8(bfr[1][0], f0, accZ);
    accZ = mfma8(bfr[1][1], f1, accZ);
    accZ = mfma8(bfr[1][2], f2, accZ);
    accZ = mfma8(bfr[1][3], f3, accZ);
    i32x4 accN = {0, 0, 0, 0};
    accN = mfma8(bfr[2][0], f0, accN);
    accN = mfma8(bfr[2][1], f1, accN);
    accN = mfma8(bfr[2][2], f2, accN);
    accN = mfma8(bfr[2][3], f3, accN);
    __builtin_amdgcn_s_setprio(0);

    // D) r/z sigmoids (accR/accZ retired ~8 MFMA-issues early)
    float gR = (float)pick4i(accR, e) * dqR;
    float gZ = (float)pick4i(accZ, e) * dqZ;
    float sr = rcp_(1.f + exp2f_(-(bf2f(xr) + gR)));       // sigmoid
    float sz = rcp_(1.f + exp2f_(-(bf2f(xz) + gZ)));

    // E) tanh + GRU update
    float gN = (float)pick4i(accN, e) * dqN;
    float nv = bf2f(xn) + sr * (gN + bn0);                 // 2*L2E-scaled
    float nn = fmaf(2.f, rcp_(1.f + exp2f_(-nv)), -1.f);   // tanh, inf-safe
    float hv = nn + sz * (hx - nn);
    hx = hv;
    h8[sel ^ 1][bb][hcol] = (signed char)(int)__builtin_rintf(hv * 127.f);
    __syncthreads();   // h8[sel^1] ready; orders next-step reads of sel
  }

  hT[hrow] = hx;
}

// ---------------------------------------------------------------------------
// Kernel 4: out[b] = elu(sum_c hT[c,b,:] @ Wf + bf); feature[c,:] = mean_b hT
__global__ __launch_bounds__(128) void finalize(const float* __restrict__ hT,
                                                const float* __restrict__ Wf,
                                                const float* __restrict__ bfv,
                                                float* __restrict__ out) {
  __shared__ float hsum[256];
  const int bid = blockIdx.x, tid = threadIdx.x;
  if (bid < 256) {
    const int b = bid;
    for (int k = tid; k < 256; k += 128)
      hsum[k] = hT[((size_t)(0 * 256 + b)) * 256 + k]
              + hT[((size_t)(1 * 256 + b)) * 256 + k]
              + hT[((size_t)(2 * 256 + b)) * 256 + k];
    __syncthreads();
    float acc = bfv[tid];
    #pragma unroll 8
    for (int k = 0; k < 256; ++k)
      acc = fmaf(hsum[k], Wf[(size_t)k * OUT_ + tid], acc);
    float rv = acc > 0.f ? acc : (__expf(acc) - 1.f);
    out[b * OUT_ + tid] = rv;
  } else {
    const int idx = bid - 256;                 // 0..5
    const int c = idx >> 1, j = ((idx & 1) << 7) + tid;
    float sum = 0.f;
    #pragma unroll 4
    for (int b = 0; b < 256; ++b)
      sum += hT[((size_t)(c * 256 + b)) * 256 + j];
    out[B_ * OUT_ + c * 256 + j] = sum * (1.f / 256.f);
  }
}

// ---------------------------------------------------------------------------
extern "C" void kernel_launch(void* const* d_in, const int* in_sizes, int n_in,
                              void* d_out, int out_size, void* d_ws, size_t ws_size,
                              hipStream_t stream) {
  const float* x   = (const float*)d_in[0];
  const float* hid = (const float*)d_in[1];
  const float* Wx  = (const float*)d_in[2];
  const float* bx  = (const float*)d_in[3];
  const float* Wh  = (const float*)d_in[4];
  const float* bh  = (const float*)d_in[5];
  const float* Wf  = (const float*)d_in[6];
  const float* bf_ = (const float*)d_in[7];
  float* out = (float*)d_out;

  char* ws = (char*)d_ws;
  u16* WxT   = (u16*)ws;                                   // 768*128 bf16 = 192 KiB
  u16* gxw   = (u16*)(ws + (1 << 18));                     // 48 MiB
  size_t off = (1 << 18) + (size_t)T_ * B_ * H3_ * 2;
  float* hTw = (float*)(ws + off);                         // 3*256*256 f32 = 768 KiB
  off += (size_t)3 * 256 * 256 * 4;
  signed char* whp8 = (signed char*)(ws + off);            // 1024*192 = 192 KiB
  off += (size_t)1024 * 192;
  float* sww = (float*)(ws + off);                         // 768 f32

  wh_scales<<<3, 256, 0, stream>>>(Wh, sww);
  prep<<<480, 256, 0, stream>>>(Wx, Wh, sww, WxT, whp8);
  gx_gemm<<<dim3(256, 4), 512, 0, stream>>>(x, WxT, bx, bh, gxw);
  cru_scan<<<192, 1024, 0, stream>>>(hid, whp8, sww, bh, gxw, hTw);
  finalize<<<262, 128, 0, stream>>>(hTw, Wf, bf_, out);
}

// Round 7
// 216.226 us; speedup vs baseline: 2.8271x; 1.1872x over previous
//
#include <hip/hip_runtime.h>

// Problem constants (B, T, IN, H, OUT) = (256, 128, 128, 256, 128)
// External tensors f32; gx workspace bf16 PRE-SCALED by log2e / 2*log2e.
//
// Round-12: R6 validated the int8 scan (absmax unchanged at 0.015625,
// scan 196 -> 104us, VGPR 48, no spill). Remaining time is 104 scan +
// ~153 non-scan. Fixes this round:
//  (a) wh_scales was 3 blocks x 256 threads with 256 serial strided loads
//      per thread (latency-bound, ~30-50us for 768KB). Now 12 blocks x
//      1024 threads, coalesced, LDS reduce -> ~3-5us.
//  (b) scan: software-pipeline the 3 gx loads (prefetch t+1 after MFMA
//      issue, consume next iter) + strength-reduced gx pointer.
// Scan structure (proven in R6): int8 Wh fragments (48 VGPRs) via
// mfma_i32_16x16x64_i8, 4 eager ds_read_b128, chain-major R4,Z4,N4 so r/z
// sigmoids overlap the N-chain drain, dequant sW*fac/127, one barrier/step.
#define B_   256
#define T_   128
#define IN_  128
#define H_   256
#define H3_  768
#define OUT_ 128

#define L2E  1.4426950408889634f

typedef unsigned short u16;
typedef u16   u16x4  __attribute__((ext_vector_type(4)));
typedef u16   u16x8  __attribute__((ext_vector_type(8)));
typedef __bf16 bf16x8 __attribute__((ext_vector_type(8)));
typedef float f32x4  __attribute__((ext_vector_type(4)));
typedef int   i32x4  __attribute__((ext_vector_type(4)));
typedef signed char c8x8 __attribute__((ext_vector_type(8)));

__device__ __forceinline__ float bf2f(u16 u) {
  unsigned int v = ((unsigned int)u) << 16;
  return __builtin_bit_cast(float, v);
}
__device__ __forceinline__ u16 f2bf(float f) {        // RNE (off hot path)
  unsigned int u = __builtin_bit_cast(unsigned int, f);
  u += 0x7fffu + ((u >> 16) & 1u);
  return (u16)(u >> 16);
}
__device__ __forceinline__ f32x4 mfma16(bf16x8 a, bf16x8 b, f32x4 c) {
  return __builtin_amdgcn_mfma_f32_16x16x32_bf16(a, b, c, 0, 0, 0);
}
__device__ __forceinline__ i32x4 mfma8(i32x4 a, i32x4 b, i32x4 c) {
  return __builtin_amdgcn_mfma_i32_16x16x64_i8(a, b, c, 0, 0, 0);
}
__device__ __forceinline__ float exp2f_(float x) {
#if __has_builtin(__builtin_amdgcn_exp2f)
  return __builtin_amdgcn_exp2f(x);
#else
  return __builtin_exp2f(x);
#endif
}
__device__ __forceinline__ float rcp_(float x) { return __builtin_amdgcn_rcpf(x); }

__device__ __forceinline__ int pick4i(i32x4 v, int e) {
  int r = v[0];
  r = (e == 1) ? v[1] : r;
  r = (e == 2) ? v[2] : r;
  r = (e == 3) ? v[3] : r;
  return r;
}

// ---------------------------------------------------------------------------
// Kernel 0: per-column scales sW[n] = max_k |Wh[k,n]| / 127.
// 12 blocks x 1024 threads: thread (kg = tid>>6, nl = tid&63) reduces 16
// k-rows for column n0+nl; 64 consecutive nl -> 256B coalesced segments.
__global__ __launch_bounds__(1024) void wh_scales(const float* __restrict__ Wh,
                                                  float* __restrict__ sw) {
  __shared__ float red[16][64];
  const int n0 = blockIdx.x * 64;              // 12 blocks cover 768 cols
  const int nl = threadIdx.x & 63, kg = threadIdx.x >> 6;   // 16 k-groups
  float m = 1e-30f;
  #pragma unroll
  for (int i = 0; i < 16; ++i)
    m = fmaxf(m, fabsf(Wh[(size_t)(kg * 16 + i) * H3_ + n0 + nl]));
  red[kg][nl] = m;
  __syncthreads();
  if (threadIdx.x < 64) {
    float v = m;                               // kg==0 partial
    #pragma unroll
    for (int i = 1; i < 16; ++i) v = fmaxf(v, red[i][nl]);
    sw[n0 + nl] = v * (1.f / 127.f);
  }
}

// ---------------------------------------------------------------------------
// Kernel 1 (fused prep):
//  blocks [0,384):  Wx (f32, 128x768) -> WxT (bf16, 768x128), unscaled
//  blocks [384,480): Wh -> whp8: INT8 fragments pre-packed per scan thread:
//    whp8[tid*192 + g*64 + kk*16 + (j8*8+j)] =
//      rint(Wh[kk*64 + quad*16 + j8*8 + j][n] / sW[n]),
//    n = g*256 + (tid>>6)*16 + (tid&15), quad = (tid&63)>>4.
__global__ __launch_bounds__(256) void prep(const float* __restrict__ Wx,
                                            const float* __restrict__ Wh,
                                            const float* __restrict__ sw,
                                            u16* __restrict__ WxT,
                                            signed char* __restrict__ whp8) {
  const int bid = blockIdx.x;
  if (bid < 384) {
    int o = bid * 256 + threadIdx.x;            // 0..98303
    int n = o >> 7, k = o & 127;
    WxT[o] = f2bf(Wx[(size_t)k * H3_ + n]);
  } else {
    int o8 = (bid - 384) * 256 + threadIdx.x;   // 0..24575 (8 bytes each)
    int j8 = o8 & 1;
    int kk = (o8 >> 1) & 3;
    int g  = (o8 >> 3) % 3;
    int tp = o8 / 24;                           // scan-kernel tid, 0..1023
    int l  = tp & 63, w = tp >> 6;
    int n  = g * 256 + w * 16 + (l & 15);
    int kbase = kk * 64 + ((l >> 4) & 3) * 16 + j8 * 8;
    float rs = rcp_(sw[n]);                     // 127 / max_k|Wh[:,n]|
    c8x8 v;
    #pragma unroll
    for (int j = 0; j < 8; ++j) {
      float q = __builtin_rintf(Wh[(size_t)(kbase + j) * H3_ + n] * rs);
      v[j] = (signed char)(int)q;
    }
    *(c8x8*)(whp8 + (size_t)o8 * 8) = v;
  }
}

// ---------------------------------------------------------------------------
// Kernel 2: gx[t*B+b][n] = bf16( (x[b,t,:]@Wx[:,n] + bx[n] + (n<512?bh[n]:0)) * sc )
// sc = L2E for r/z gates (n<512), 2*L2E for n gate. M=32768, N=768, K=128.
// Tile 128(M) x 192(N), 512 threads (8 waves as 2Mx4N). C staged via LDS.
__global__ __launch_bounds__(512) void gx_gemm(const float* __restrict__ x,
                                               const u16* __restrict__ WxT,
                                               const float* __restrict__ bx,
                                               const float* __restrict__ bh,
                                               u16* __restrict__ gxw) {
  __shared__ __align__(16) char smem[(128 * 136 + 192 * 136) * 2];  // 87 KB
  u16 (*As)[136] = (u16(*)[136])smem;
  u16 (*Bs)[136] = (u16(*)[136])(smem + 128 * 136 * 2);
  u16 (*St)[204] = (u16(*)[204])smem;       // aliases As/Bs after 2nd barrier

  const int mt = blockIdx.x;                  // 0..255
  const int n0 = blockIdx.y * 192;            // 0,192,384,576
  const int m0 = mt * 128;
  const int t  = mt >> 1;
  const int brow0 = (mt & 1) * 128;
  const int tid = threadIdx.x;
  const int w = tid >> 6, lane = tid & 63, quad = lane >> 4, r = lane & 15;
  const int wm = w >> 2, wn = w & 3;          // 2 x 4 wave grid

  {  // A tile: 128 rows x 128 cols, f32 -> bf16; 4-lane groups read 64B
    int row = tid >> 2;
    int colc = (tid & 3) * 4;
    const float* s = x + ((size_t)(brow0 + row) * T_ + t) * IN_ + colc;
    #pragma unroll
    for (int c4 = 0; c4 < 8; ++c4) {
      f32x4 v = *(const f32x4*)(s + c4 * 16);
      u16x4 b;
      b[0] = f2bf(v[0]); b[1] = f2bf(v[1]); b[2] = f2bf(v[2]); b[3] = f2bf(v[3]);
      *(u16x4*)&As[row][colc + c4 * 16] = b;
    }
  }
  {  // B tile [n][k] from WxT: 192 x 128 u16
    #pragma unroll
    for (int i = 0; i < 6; ++i) {
      int idx = tid + i * 512;                // 0..3071
      int row = idx >> 4, col8 = (idx & 15) * 8;
      *(u16x8*)&Bs[row][col8] = *(const u16x8*)(WxT + (size_t)(n0 + row) * IN_ + col8);
    }
  }
  __syncthreads();

  f32x4 acc[4][3];
  #pragma unroll
  for (int i = 0; i < 4; ++i)
    #pragma unroll
    for (int j = 0; j < 3; ++j)
      acc[i][j] = (f32x4){0.f, 0.f, 0.f, 0.f};

  #pragma unroll
  for (int kk = 0; kk < 4; ++kk) {
    bf16x8 a[4];
    #pragma unroll
    for (int m2 = 0; m2 < 4; ++m2)
      a[m2] = *(const bf16x8*)&As[wm * 64 + m2 * 16 + r][kk * 32 + quad * 8];
    #pragma unroll
    for (int n2 = 0; n2 < 3; ++n2) {
      bf16x8 b = *(const bf16x8*)&Bs[wn * 48 + n2 * 16 + r][kk * 32 + quad * 8];
      #pragma unroll
      for (int m2 = 0; m2 < 4; ++m2)
        acc[m2][n2] = mfma16(a[m2], b, acc[m2][n2]);
    }
  }

  __syncthreads();   // all LDS reads done; safe to alias As/Bs as St

  #pragma unroll
  for (int m2 = 0; m2 < 4; ++m2)
    #pragma unroll
    for (int n2 = 0; n2 < 3; ++n2) {
      int nl = wn * 48 + n2 * 16 + r;                  // local col (C col = lane&15)
      int n  = n0 + nl;
      float sc = (n < 512) ? L2E : (2.f * L2E);
      float bias = bx[n] + (n < 512 ? bh[n] : 0.f);
      #pragma unroll
      for (int e = 0; e < 4; ++e) {                    // C row = quad*4 + e
        int mrow = wm * 64 + m2 * 16 + quad * 4 + e;
        St[mrow][nl] = f2bf((acc[m2][n2][e] + bias) * sc);
      }
    }
  __syncthreads();

  #pragma unroll
  for (int i = 0; i < 6; ++i) {                        // coalesced 16B stores
    int idx = tid + i * 512;                           // 0..3071
    int row = idx / 24, c8 = (idx % 24) * 8;
    *(u16x8*)(gxw + (size_t)(m0 + row) * H3_ + n0 + c8) = *(const u16x8*)&St[row][c8];
  }
}

// ---------------------------------------------------------------------------
// Kernel 3: the scan, INT8. 192 blocks x 1024 threads, 4 batch rows/block.
// Per step per thread: 4 eager ds_read_b128 -> 12 MFMA i32_16x16x64_i8 as
// R4,Z4,N4 chains -> prefetch next step's 3 gx values (consumed next iter)
// -> dequant epilogue (r/z sigmoids overlap N drain) -> ds_write_b8 ->
// one barrier. 48 VGPR frag file + ~8 live = no spill (WRITE_SIZE tripwire).
__global__ __launch_bounds__(1024)
void cru_scan(const float* __restrict__ hid,
              const signed char* __restrict__ whp8,
              const float* __restrict__ sw,
              const float* __restrict__ bh,
              const u16*  __restrict__ gx,
              float* __restrict__ hT) {
  __shared__ __align__(16) signed char h8[2][4][288];   // double buffer, 2.3 KB

  const int bid = blockIdx.x;           // 192 blocks
  const int c   = bid >> 6;             // component 0..2
  const int b0  = (bid & 63) << 2;      // batch row group of 4
  const int tid = threadIdx.x;
  const int lane = tid & 63, quad = lane >> 4, m = lane & 15;
  const int w  = tid >> 6;              // wave 0..15
  const int bb = m & 3;                 // batch row within group
  const int e  = m >> 2;                // kept accumulator element
  const int hcol = w * 16 + quad * 4 + e;   // owned n-col 0..255

  // --- one-time fragment load: 192 B contiguous per thread, coalesced ---
  i32x4 bfr[3][4];
  {
    const signed char* wp = whp8 + (size_t)tid * 192;
    #pragma unroll
    for (int g = 0; g < 3; ++g)
      #pragma unroll
      for (int kk = 0; kk < 4; ++kk)
        bfr[g][kk] = *(const i32x4*)(wp + g * 64 + kk * 16);
  }

  // --- dequant constants: gh = acc * sW/127, then gate prescale ---
  const float dqR = sw[hcol]       * (L2E / 127.f);
  const float dqZ = sw[256 + hcol] * (L2E / 127.f);
  const float dqN = sw[512 + hcol] * (2.f * L2E / 127.f);

  // --- this lane's h element: h[bb][hcol] ---
  const size_t hrow = (size_t)(c * 256 + b0 + bb) * 256 + hcol;
  float hx = hid[hrow];
  h8[0][bb][hcol] = (signed char)(int)__builtin_rintf(fminf(fmaxf(hx, -1.f), 1.f) * 127.f);
  const float bn0 = bh[512 + hcol] * (2.f * L2E);

  const u16* gxp = gx + (size_t)(b0 + bb) * H3_ + hcol;
  const int rbase = bb * 288 + quad * 16;      // B-frag read base (bytes)

  // prefetch t=0 gx values
  u16 xr = gxp[0], xz = gxp[256], xn = gxp[512];
  const u16* gxs = gxp + (size_t)(B_ * H3_);   // points at t+1

  __syncthreads();

  #pragma unroll 2
  for (int t = 0; t < T_; ++t) {
    const int sel = t & 1;

    // A) eager B-frag reads (4 x ds_read_b128, 16 distinct addrs, 4-way
    //    same-address broadcast, 2-way bank aliasing = free)
    const signed char* hb = &h8[sel][0][0];
    i32x4 f0 = *(const i32x4*)(hb + rbase);
    i32x4 f1 = *(const i32x4*)(hb + rbase + 64);
    i32x4 f2 = *(const i32x4*)(hb + rbase + 128);
    i32x4 f3 = *(const i32x4*)(hb + rbase + 192);

    // B) chain-ordered MFMA: R,Z retire early; their sigmoids overlap N
    __builtin_amdgcn_s_setprio(1);
    i32x4 accR = {0, 0, 0, 0};
    accR = mfma8(bfr[0][0], f0, accR);
    accR = mfma8(bfr[0][1], f1, accR);
    accR = mfma8(bfr[0][2], f2, accR);
    accR = mfma8(bfr[0][3], f3, accR);
    i32x4 accZ = {0, 0, 0, 0};
    accZ = mfma8(bfr[1][0], f0, accZ);
    accZ = mfma8(bfr[1][1], f1, accZ);
    accZ = mfma8(bfr[1][2], f2, accZ);
    accZ = mfma8(bfr[1][3], f3, accZ);
    i32x4 accN = {0, 0, 0, 0};
    accN = mfma8(bfr[2][0], f0, accN);
    accN = mfma8(bfr[2][1], f1, accN);
    accN = mfma8(bfr[2][2], f2, accN);
    accN = mfma8(bfr[2][3], f3, accN);
    __builtin_amdgcn_s_setprio(0);

    // C) prefetch NEXT step's gx (latency hidden under epilogue + next
    //    step's LDS/MFMA phase; values consumed next iteration)
    u16 nxr = 0, nxz = 0, nxn = 0;
    if (t + 1 < T_) { nxr = gxs[0]; nxz = gxs[256]; nxn = gxs[512]; }
    gxs += B_ * H3_;

    // D) r/z sigmoids (accR/accZ retired ~8 MFMA-issues early)
    float gR = (float)pick4i(accR, e) * dqR;
    float gZ = (float)pick4i(accZ, e) * dqZ;
    float sr = rcp_(1.f + exp2f_(-(bf2f(xr) + gR)));       // sigmoid
    float sz = rcp_(1.f + exp2f_(-(bf2f(xz) + gZ)));

    // E) tanh + GRU update
    float gN = (float)pick4i(accN, e) * dqN;
    float nv = bf2f(xn) + sr * (gN + bn0);                 // 2*L2E-scaled
    float nn = fmaf(2.f, rcp_(1.f + exp2f_(-nv)), -1.f);   // tanh, inf-safe
    float hv = nn + sz * (hx - nn);
    hx = hv;
    h8[sel ^ 1][bb][hcol] = (signed char)(int)__builtin_rintf(hv * 127.f);
    xr = nxr; xz = nxz; xn = nxn;
    __syncthreads();   // h8[sel^1] ready; orders next-step reads of sel
  }

  hT[hrow] = hx;
}

// ---------------------------------------------------------------------------
// Kernel 4: out[b] = elu(sum_c hT[c,b,:] @ Wf + bf); feature[c,:] = mean_b hT
__global__ __launch_bounds__(128) void finalize(const float* __restrict__ hT,
                                                const float* __restrict__ Wf,
                                                const float* __restrict__ bfv,
                                                float* __restrict__ out) {
  __shared__ float hsum[256];
  const int bid = blockIdx.x, tid = threadIdx.x;
  if (bid < 256) {
    const int b = bid;
    for (int k = tid; k < 256; k += 128)
      hsum[k] = hT[((size_t)(0 * 256 + b)) * 256 + k]
              + hT[((size_t)(1 * 256 + b)) * 256 + k]
              + hT[((size_t)(2 * 256 + b)) * 256 + k];
    __syncthreads();
    float acc = bfv[tid];
    #pragma unroll 8
    for (int k = 0; k < 256; ++k)
      acc = fmaf(hsum[k], Wf[(size_t)k * OUT_ + tid], acc);
    float rv = acc > 0.f ? acc : (__expf(acc) - 1.f);
    out[b * OUT_ + tid] = rv;
  } else {
    const int idx = bid - 256;                 // 0..5
    const int c = idx >> 1, j = ((idx & 1) << 7) + tid;
    float sum = 0.f;
    #pragma unroll 4
    for (int b = 0; b < 256; ++b)
      sum += hT[((size_t)(c * 256 + b)) * 256 + j];
    out[B_ * OUT_ + c * 256 + j] = sum * (1.f / 256.f);
  }
}

// ---------------------------------------------------------------------------
extern "C" void kernel_launch(void* const* d_in, const int* in_sizes, int n_in,
                              void* d_out, int out_size, void* d_ws, size_t ws_size,
                              hipStream_t stream) {
  const float* x   = (const float*)d_in[0];
  const float* hid = (const float*)d_in[1];
  const float* Wx  = (const float*)d_in[2];
  const float* bx  = (const float*)d_in[3];
  const float* Wh  = (const float*)d_in[4];
  const float* bh  = (const float*)d_in[5];
  const float* Wf  = (const float*)d_in[6];
  const float* bf_ = (const float*)d_in[7];
  float* out = (float*)d_out;

  char* ws = (char*)d_ws;
  u16* WxT   = (u16*)ws;                                   // 768*128 bf16 = 192 KiB
  u16* gxw   = (u16*)(ws + (1 << 18));                     // 48 MiB
  size_t off = (1 << 18) + (size_t)T_ * B_ * H3_ * 2;
  float* hTw = (float*)(ws + off);                         // 3*256*256 f32 = 768 KiB
  off += (size_t)3 * 256 * 256 * 4;
  signed char* whp8 = (signed char*)(ws + off);            // 1024*192 = 192 KiB
  off += (size_t)1024 * 192;
  float* sww = (float*)(ws + off);                         // 768 f32

  wh_scales<<<12, 1024, 0, stream>>>(Wh, sww);
  prep<<<480, 256, 0, stream>>>(Wx, Wh, sww, WxT, whp8);
  gx_gemm<<<dim3(256, 4), 512, 0, stream>>>(x, WxT, bx, bh, gxw);
  cru_scan<<<192, 1024, 0, stream>>>(hid, whp8, sww, bh, gxw, hTw);
  finalize<<<262, 128, 0, stream>>>(hTw, Wf, bf_, out);
}

// Round 8
// 203.818 us; speedup vs baseline: 2.9992x; 1.0609x over previous
//
#include <hip/hip_runtime.h>

// Problem constants (B, T, IN, H, OUT) = (256, 128, 128, 256, 128)
// External tensors f32; gx workspace bf16 PRE-SCALED by log2e / 2*log2e.
//
// Round-13:
//  (a) scan MFMA order chain-major -> kk-major (R,Z,N per kk): chain-major
//      was a 4-deep dependent accumulator chain per gate; kk-major gives
//      3-way ILP so the matrix pipe doesn't idle between dependent MFMAs.
//  (b) kernel merge 5 -> 4: K1 = {Wx-transpose U wh_scales},
//      K2 = {gx_gemm U Wh-int8-pack} — independent chains co-run instead of
//      serializing on the stream; -2 launch boundaries.
//  (c) unconditional gx prefetch (1-past-end lands in mapped hTw, discarded).
// Scan structure (validated R6/R7): int8 Wh fragments (48 VGPRs) via
// mfma_i32_16x16x64_i8, 4 eager ds_read_b128 (4-way dup = HW broadcast),
// dequant sW*fac/127, one barrier/step. Floor: 192 MFMA/block/step ~ 980cyc
// (decomposition-invariant; cross-block h-exchange per step impossible).
#define B_   256
#define T_   128
#define IN_  128
#define H_   256
#define H3_  768
#define OUT_ 128

#define L2E  1.4426950408889634f

typedef unsigned short u16;
typedef u16   u16x4  __attribute__((ext_vector_type(4)));
typedef u16   u16x8  __attribute__((ext_vector_type(8)));
typedef __bf16 bf16x8 __attribute__((ext_vector_type(8)));
typedef float f32x4  __attribute__((ext_vector_type(4)));
typedef int   i32x4  __attribute__((ext_vector_type(4)));
typedef signed char c8x8 __attribute__((ext_vector_type(8)));

__device__ __forceinline__ float bf2f(u16 u) {
  unsigned int v = ((unsigned int)u) << 16;
  return __builtin_bit_cast(float, v);
}
__device__ __forceinline__ u16 f2bf(float f) {        // RNE (off hot path)
  unsigned int u = __builtin_bit_cast(unsigned int, f);
  u += 0x7fffu + ((u >> 16) & 1u);
  return (u16)(u >> 16);
}
__device__ __forceinline__ f32x4 mfma16(bf16x8 a, bf16x8 b, f32x4 c) {
  return __builtin_amdgcn_mfma_f32_16x16x32_bf16(a, b, c, 0, 0, 0);
}
__device__ __forceinline__ i32x4 mfma8(i32x4 a, i32x4 b, i32x4 c) {
  return __builtin_amdgcn_mfma_i32_16x16x64_i8(a, b, c, 0, 0, 0);
}
__device__ __forceinline__ float exp2f_(float x) {
#if __has_builtin(__builtin_amdgcn_exp2f)
  return __builtin_amdgcn_exp2f(x);
#else
  return __builtin_exp2f(x);
#endif
}
__device__ __forceinline__ float rcp_(float x) { return __builtin_amdgcn_rcpf(x); }

__device__ __forceinline__ int pick4i(i32x4 v, int e) {
  int r = v[0];
  r = (e == 1) ? v[1] : r;
  r = (e == 2) ? v[2] : r;
  r = (e == 3) ? v[3] : r;
  return r;
}

// ---------------------------------------------------------------------------
// K1 (prep0): blocks [0,96): Wx (f32, 128x768) -> WxT (bf16, 768x128)
//             blocks [96,108): sW[n] = max_k |Wh[k,n]| / 127
// Independent halves co-run in one dispatch.
__global__ __launch_bounds__(1024) void prep0(const float* __restrict__ Wx,
                                              const float* __restrict__ Wh,
                                              u16* __restrict__ WxT,
                                              float* __restrict__ sw) {
  const int bid = blockIdx.x;
  if (bid < 96) {
    int o = bid * 1024 + threadIdx.x;           // 0..98303
    int n = o >> 7, k = o & 127;
    WxT[o] = f2bf(Wx[(size_t)k * H3_ + n]);
  } else {
    __shared__ float red[16][64];
    const int n0 = (bid - 96) * 64;             // 12 blocks cover 768 cols
    const int nl = threadIdx.x & 63, kg = threadIdx.x >> 6;   // 16 k-groups
    float m = 1e-30f;
    #pragma unroll
    for (int i = 0; i < 16; ++i)
      m = fmaxf(m, fabsf(Wh[(size_t)(kg * 16 + i) * H3_ + n0 + nl]));
    red[kg][nl] = m;
    __syncthreads();
    if (threadIdx.x < 64) {
      float v = m;                              // kg==0 partial
      #pragma unroll
      for (int i = 1; i < 16; ++i) v = fmaxf(v, red[i][nl]);
      sw[n0 + nl] = v * (1.f / 127.f);
    }
  }
}

// ---------------------------------------------------------------------------
// K2 (prep1): blocks [0,1024): gx GEMM (mt = bid&255, n0 = (bid>>8)*192)
//             blocks [1024,1072): Wh -> whp8 int8 fragment pack
// gx[t*B+b][n] = bf16( (x[b,t,:]@Wx[:,n] + bx[n] + (n<512?bh[n]:0)) * sc ),
// sc = L2E (r,z) / 2*L2E (n). Tile 128x192, 512 thr, C staged via LDS.
// whp8[tid*192 + g*64 + kk*16 + j] = rint(Wh[kk*64+quad*16+j][n] / sW[n]).
__global__ __launch_bounds__(512) void prep1(const float* __restrict__ x,
                                             const u16* __restrict__ WxT,
                                             const float* __restrict__ bx,
                                             const float* __restrict__ bh,
                                             const float* __restrict__ Wh,
                                             const float* __restrict__ sw,
                                             u16* __restrict__ gxw,
                                             signed char* __restrict__ whp8) {
  __shared__ __align__(16) char smem[(128 * 136 + 192 * 136) * 2];  // 87 KB
  const int bid = blockIdx.x;
  const int tid = threadIdx.x;

  if (bid >= 1024) {                            // ---- Wh int8 pack ----
    int o8 = (bid - 1024) * 512 + tid;          // 0..24575 (8 bytes each)
    int j8 = o8 & 1;
    int kk = (o8 >> 1) & 3;
    int g  = (o8 >> 3) % 3;
    int tp = o8 / 24;                           // scan-kernel tid, 0..1023
    int l  = tp & 63, w = tp >> 6;
    int n  = g * 256 + w * 16 + (l & 15);
    int kbase = kk * 64 + ((l >> 4) & 3) * 16 + j8 * 8;
    float rs = rcp_(sw[n]);                     // 127 / max_k|Wh[:,n]|
    c8x8 v;
    #pragma unroll
    for (int j = 0; j < 8; ++j) {
      float q = __builtin_rintf(Wh[(size_t)(kbase + j) * H3_ + n] * rs);
      v[j] = (signed char)(int)q;
    }
    *(c8x8*)(whp8 + (size_t)o8 * 8) = v;
    return;
  }

  // ---- gx GEMM ----
  u16 (*As)[136] = (u16(*)[136])smem;
  u16 (*Bs)[136] = (u16(*)[136])(smem + 128 * 136 * 2);
  u16 (*St)[204] = (u16(*)[204])smem;           // aliases after 2nd barrier

  const int mt = bid & 255;
  const int n0 = (bid >> 8) * 192;              // 0,192,384,576
  const int m0 = mt * 128;
  const int t  = mt >> 1;
  const int brow0 = (mt & 1) * 128;
  const int w = tid >> 6, lane = tid & 63, quad = lane >> 4, r = lane & 15;
  const int wm = w >> 2, wn = w & 3;            // 2 x 4 wave grid

  {  // A tile: 128 rows x 128 cols, f32 -> bf16; 4-lane groups read 64B
    int row = tid >> 2;
    int colc = (tid & 3) * 4;
    const float* s = x + ((size_t)(brow0 + row) * T_ + t) * IN_ + colc;
    #pragma unroll
    for (int c4 = 0; c4 < 8; ++c4) {
      f32x4 v = *(const f32x4*)(s + c4 * 16);
      u16x4 b;
      b[0] = f2bf(v[0]); b[1] = f2bf(v[1]); b[2] = f2bf(v[2]); b[3] = f2bf(v[3]);
      *(u16x4*)&As[row][colc + c4 * 16] = b;
    }
  }
  {  // B tile [n][k] from WxT: 192 x 128 u16
    #pragma unroll
    for (int i = 0; i < 6; ++i) {
      int idx = tid + i * 512;                  // 0..3071
      int row = idx >> 4, col8 = (idx & 15) * 8;
      *(u16x8*)&Bs[row][col8] = *(const u16x8*)(WxT + (size_t)(n0 + row) * IN_ + col8);
    }
  }
  __syncthreads();

  f32x4 acc[4][3];
  #pragma unroll
  for (int i = 0; i < 4; ++i)
    #pragma unroll
    for (int j = 0; j < 3; ++j)
      acc[i][j] = (f32x4){0.f, 0.f, 0.f, 0.f};

  #pragma unroll
  for (int kk = 0; kk < 4; ++kk) {
    bf16x8 a[4];
    #pragma unroll
    for (int m2 = 0; m2 < 4; ++m2)
      a[m2] = *(const bf16x8*)&As[wm * 64 + m2 * 16 + r][kk * 32 + quad * 8];
    #pragma unroll
    for (int n2 = 0; n2 < 3; ++n2) {
      bf16x8 b = *(const bf16x8*)&Bs[wn * 48 + n2 * 16 + r][kk * 32 + quad * 8];
      #pragma unroll
      for (int m2 = 0; m2 < 4; ++m2)
        acc[m2][n2] = mfma16(a[m2], b, acc[m2][n2]);
    }
  }

  __syncthreads();   // all LDS reads done; safe to alias As/Bs as St

  #pragma unroll
  for (int m2 = 0; m2 < 4; ++m2)
    #pragma unroll
    for (int n2 = 0; n2 < 3; ++n2) {
      int nl = wn * 48 + n2 * 16 + r;           // local col (C col = lane&15)
      int n  = n0 + nl;
      float sc = (n < 512) ? L2E : (2.f * L2E);
      float bias = bx[n] + (n < 512 ? bh[n] : 0.f);
      #pragma unroll
      for (int e = 0; e < 4; ++e) {             // C row = quad*4 + e
        int mrow = wm * 64 + m2 * 16 + quad * 4 + e;
        St[mrow][nl] = f2bf((acc[m2][n2][e] + bias) * sc);
      }
    }
  __syncthreads();

  #pragma unroll
  for (int i = 0; i < 6; ++i) {                 // coalesced 16B stores
    int idx = tid + i * 512;                    // 0..3071
    int row = idx / 24, c8 = (idx % 24) * 8;
    *(u16x8*)(gxw + (size_t)(m0 + row) * H3_ + n0 + c8) = *(const u16x8*)&St[row][c8];
  }
}

// ---------------------------------------------------------------------------
// K3: the scan, INT8. 192 blocks x 1024 threads, 4 batch rows/block.
// Per step: 4 eager ds_read_b128 -> 12 MFMA kk-MAJOR (R,Z,N per kk: 3-way
// ILP, no 4-deep dependent chains) -> unconditional gx(t+1) prefetch ->
// dequant epilogue -> ds_write_b8 -> one barrier.
__global__ __launch_bounds__(1024)
void cru_scan(const float* __restrict__ hid,
              const signed char* __restrict__ whp8,
              const float* __restrict__ sw,
              const float* __restrict__ bh,
              const u16*  __restrict__ gx,
              float* __restrict__ hT) {
  __shared__ __align__(16) signed char h8[2][4][288];   // double buffer, 2.3 KB

  const int bid = blockIdx.x;           // 192 blocks
  const int c   = bid >> 6;             // component 0..2
  const int b0  = (bid & 63) << 2;      // batch row group of 4
  const int tid = threadIdx.x;
  const int lane = tid & 63, quad = lane >> 4, m = lane & 15;
  const int w  = tid >> 6;              // wave 0..15
  const int bb = m & 3;                 // batch row within group
  const int e  = m >> 2;                // kept accumulator element
  const int hcol = w * 16 + quad * 4 + e;   // owned n-col 0..255

  // --- one-time fragment load: 192 B contiguous per thread, coalesced ---
  i32x4 bfr[3][4];
  {
    const signed char* wp = whp8 + (size_t)tid * 192;
    #pragma unroll
    for (int g = 0; g < 3; ++g)
      #pragma unroll
      for (int kk = 0; kk < 4; ++kk)
        bfr[g][kk] = *(const i32x4*)(wp + g * 64 + kk * 16);
  }

  // --- dequant constants: gh = acc * sW/127, then gate prescale ---
  const float dqR = sw[hcol]       * (L2E / 127.f);
  const float dqZ = sw[256 + hcol] * (L2E / 127.f);
  const float dqN = sw[512 + hcol] * (2.f * L2E / 127.f);

  // --- this lane's h element: h[bb][hcol] ---
  const size_t hrow = (size_t)(c * 256 + b0 + bb) * 256 + hcol;
  float hx = hid[hrow];
  h8[0][bb][hcol] = (signed char)(int)__builtin_rintf(fminf(fmaxf(hx, -1.f), 1.f) * 127.f);
  const float bn0 = bh[512 + hcol] * (2.f * L2E);

  const u16* gxp = gx + (size_t)(b0 + bb) * H3_ + hcol;
  const int rbase = bb * 288 + quad * 16;      // B-frag read base (bytes)

  // prefetch t=0 gx values
  u16 xr = gxp[0], xz = gxp[256], xn = gxp[512];
  const u16* gxs = gxp + (size_t)(B_ * H3_);   // points at t+1

  __syncthreads();

  #pragma unroll 2
  for (int t = 0; t < T_; ++t) {
    const int sel = t & 1;

    // A) eager B-frag reads (4 x ds_read_b128, 16 distinct addrs, 4-way
    //    same-address broadcast, 2-way bank aliasing = free)
    const signed char* hb = &h8[sel][0][0];
    i32x4 f0 = *(const i32x4*)(hb + rbase);
    i32x4 f1 = *(const i32x4*)(hb + rbase + 64);
    i32x4 f2 = *(const i32x4*)(hb + rbase + 128);
    i32x4 f3 = *(const i32x4*)(hb + rbase + 192);

    // B) kk-major MFMA: 3 independent accumulator chains interleaved
    __builtin_amdgcn_s_setprio(1);
    i32x4 accR = {0, 0, 0, 0};
    i32x4 accZ = {0, 0, 0, 0};
    i32x4 accN = {0, 0, 0, 0};
    accR = mfma8(bfr[0][0], f0, accR);
    accZ = mfma8(bfr[1][0], f0, accZ);
    accN = mfma8(bfr[2][0], f0, accN);
    accR = mfma8(bfr[0][1], f1, accR);
    accZ = mfma8(bfr[1][1], f1, accZ);
    accN = mfma8(bfr[2][1], f1, accN);
    accR = mfma8(bfr[0][2], f2, accR);
    accZ = mfma8(bfr[1][2], f2, accZ);
    accN = mfma8(bfr[2][2], f2, accN);
    accR = mfma8(bfr[0][3], f3, accR);
    accZ = mfma8(bfr[1][3], f3, accZ);
    accN = mfma8(bfr[2][3], f3, accN);
    __builtin_amdgcn_s_setprio(0);

    // C) unconditional gx(t+1) prefetch (t=127 reads land in mapped hTw
    //    region; values discarded)
    u16 nxr = gxs[0], nxz = gxs[256], nxn = gxs[512];
    gxs += B_ * H3_;

    // D) r/z sigmoids
    float gR = (float)pick4i(accR, e) * dqR;
    float gZ = (float)pick4i(accZ, e) * dqZ;
    float sr = rcp_(1.f + exp2f_(-(bf2f(xr) + gR)));       // sigmoid
    float sz = rcp_(1.f + exp2f_(-(bf2f(xz) + gZ)));

    // E) tanh + GRU update
    float gN = (float)pick4i(accN, e) * dqN;
    float nv = bf2f(xn) + sr * (gN + bn0);                 // 2*L2E-scaled
    float nn = fmaf(2.f, rcp_(1.f + exp2f_(-nv)), -1.f);   // tanh, inf-safe
    float hv = nn + sz * (hx - nn);
    hx = hv;
    h8[sel ^ 1][bb][hcol] = (signed char)(int)__builtin_rintf(hv * 127.f);
    xr = nxr; xz = nxz; xn = nxn;
    __syncthreads();   // h8[sel^1] ready; orders next-step reads of sel
  }

  hT[hrow] = hx;
}

// ---------------------------------------------------------------------------
// K4: out[b] = elu(sum_c hT[c,b,:] @ Wf + bf); feature[c,:] = mean_b hT
__global__ __launch_bounds__(128) void finalize(const float* __restrict__ hT,
                                                const float* __restrict__ Wf,
                                                const float* __restrict__ bfv,
                                                float* __restrict__ out) {
  __shared__ float hsum[256];
  const int bid = blockIdx.x, tid = threadIdx.x;
  if (bid < 256) {
    const int b = bid;
    for (int k = tid; k < 256; k += 128)
      hsum[k] = hT[((size_t)(0 * 256 + b)) * 256 + k]
              + hT[((size_t)(1 * 256 + b)) * 256 + k]
              + hT[((size_t)(2 * 256 + b)) * 256 + k];
    __syncthreads();
    float acc = bfv[tid];
    #pragma unroll 8
    for (int k = 0; k < 256; ++k)
      acc = fmaf(hsum[k], Wf[(size_t)k * OUT_ + tid], acc);
    float rv = acc > 0.f ? acc : (__expf(acc) - 1.f);
    out[b * OUT_ + tid] = rv;
  } else {
    const int idx = bid - 256;                 // 0..5
    const int c = idx >> 1, j = ((idx & 1) << 7) + tid;
    float sum = 0.f;
    #pragma unroll 4
    for (int b = 0; b < 256; ++b)
      sum += hT[((size_t)(c * 256 + b)) * 256 + j];
    out[B_ * OUT_ + c * 256 + j] = sum * (1.f / 256.f);
  }
}

// ---------------------------------------------------------------------------
extern "C" void kernel_launch(void* const* d_in, const int* in_sizes, int n_in,
                              void* d_out, int out_size, void* d_ws, size_t ws_size,
                              hipStream_t stream) {
  const float* x   = (const float*)d_in[0];
  const float* hid = (const float*)d_in[1];
  const float* Wx  = (const float*)d_in[2];
  const float* bx  = (const float*)d_in[3];
  const float* Wh  = (const float*)d_in[4];
  const float* bh  = (const float*)d_in[5];
  const float* Wf  = (const float*)d_in[6];
  const float* bf_ = (const float*)d_in[7];
  float* out = (float*)d_out;

  char* ws = (char*)d_ws;
  u16* WxT   = (u16*)ws;                                   // 768*128 bf16 = 192 KiB
  u16* gxw   = (u16*)(ws + (1 << 18));                     // 48 MiB
  size_t off = (1 << 18) + (size_t)T_ * B_ * H3_ * 2;
  float* hTw = (float*)(ws + off);                         // 3*256*256 f32 = 768 KiB
  off += (size_t)3 * 256 * 256 * 4;
  signed char* whp8 = (signed char*)(ws + off);            // 1024*192 = 192 KiB
  off += (size_t)1024 * 192;
  float* sww = (float*)(ws + off);                         // 768 f32

  prep0<<<108, 1024, 0, stream>>>(Wx, Wh, WxT, sww);
  prep1<<<1072, 512, 0, stream>>>(x, WxT, bx, bh, Wh, sww, gxw, whp8);
  cru_scan<<<192, 1024, 0, stream>>>(hid, whp8, sww, bh, gxw, hTw);
  finalize<<<262, 128, 0, stream>>>(hTw, Wf, bf_, out);
}

// Round 9
// 194.536 us; speedup vs baseline: 3.1423x; 1.0477x over previous
//
#include <hip/hip_runtime.h>

// Problem constants (B, T, IN, H, OUT) = (256, 128, 128, 256, 128)
// External tensors f32; gx workspace bf16 PRE-SCALED by log2e / 2*log2e.
//
// Round-14: non-scan time has been ~106us ALL session (R0/R3/R8) while scan
// went 242->96. Attack prep1 (the gx GEMM):
//  (a) N-tile 192 -> 384: blocks 1024 -> 512, B-LDS 96KB + A 34KB = 139KB
//      (1 block/CU), x re-read 4x -> 2x (~65MB less effective traffic).
//  (b) Wh-pack blocks moved to grid FRONT (bid<48): they depend only on sw,
//      and at the tail they serialized ~10-15us of latency-bound loads.
// Scan (96us, ~1.8x of its 980-cyc decomposition-invariant MFMA floor),
// prep0, finalize frozen. Tripwires: scan VGPR 48 / WRITE 768KB / absmax
// 0.015625 unchanged.
#define B_   256
#define T_   128
#define IN_  128
#define H_   256
#define H3_  768
#define OUT_ 128

#define L2E  1.4426950408889634f

typedef unsigned short u16;
typedef u16   u16x4  __attribute__((ext_vector_type(4)));
typedef u16   u16x8  __attribute__((ext_vector_type(8)));
typedef __bf16 bf16x8 __attribute__((ext_vector_type(8)));
typedef float f32x4  __attribute__((ext_vector_type(4)));
typedef int   i32x4  __attribute__((ext_vector_type(4)));
typedef signed char c8x8 __attribute__((ext_vector_type(8)));

__device__ __forceinline__ float bf2f(u16 u) {
  unsigned int v = ((unsigned int)u) << 16;
  return __builtin_bit_cast(float, v);
}
__device__ __forceinline__ u16 f2bf(float f) {        // RNE (off hot path)
  unsigned int u = __builtin_bit_cast(unsigned int, f);
  u += 0x7fffu + ((u >> 16) & 1u);
  return (u16)(u >> 16);
}
__device__ __forceinline__ f32x4 mfma16(bf16x8 a, bf16x8 b, f32x4 c) {
  return __builtin_amdgcn_mfma_f32_16x16x32_bf16(a, b, c, 0, 0, 0);
}
__device__ __forceinline__ i32x4 mfma8(i32x4 a, i32x4 b, i32x4 c) {
  return __builtin_amdgcn_mfma_i32_16x16x64_i8(a, b, c, 0, 0, 0);
}
__device__ __forceinline__ float exp2f_(float x) {
#if __has_builtin(__builtin_amdgcn_exp2f)
  return __builtin_amdgcn_exp2f(x);
#else
  return __builtin_exp2f(x);
#endif
}
__device__ __forceinline__ float rcp_(float x) { return __builtin_amdgcn_rcpf(x); }

__device__ __forceinline__ int pick4i(i32x4 v, int e) {
  int r = v[0];
  r = (e == 1) ? v[1] : r;
  r = (e == 2) ? v[2] : r;
  r = (e == 3) ? v[3] : r;
  return r;
}

// ---------------------------------------------------------------------------
// K1 (prep0): blocks [0,96): Wx (f32, 128x768) -> WxT (bf16, 768x128)
//             blocks [96,108): sW[n] = max_k |Wh[k,n]| / 127
__global__ __launch_bounds__(1024) void prep0(const float* __restrict__ Wx,
                                              const float* __restrict__ Wh,
                                              u16* __restrict__ WxT,
                                              float* __restrict__ sw) {
  const int bid = blockIdx.x;
  if (bid < 96) {
    int o = bid * 1024 + threadIdx.x;           // 0..98303
    int n = o >> 7, k = o & 127;
    WxT[o] = f2bf(Wx[(size_t)k * H3_ + n]);
  } else {
    __shared__ float red[16][64];
    const int n0 = (bid - 96) * 64;             // 12 blocks cover 768 cols
    const int nl = threadIdx.x & 63, kg = threadIdx.x >> 6;   // 16 k-groups
    float m = 1e-30f;
    #pragma unroll
    for (int i = 0; i < 16; ++i)
      m = fmaxf(m, fabsf(Wh[(size_t)(kg * 16 + i) * H3_ + n0 + nl]));
    red[kg][nl] = m;
    __syncthreads();
    if (threadIdx.x < 64) {
      float v = m;                              // kg==0 partial
      #pragma unroll
      for (int i = 1; i < 16; ++i) v = fmaxf(v, red[i][nl]);
      sw[n0 + nl] = v * (1.f / 127.f);
    }
  }
}

// ---------------------------------------------------------------------------
// K2 (prep1): blocks [0,48):   Wh -> whp8 int8 fragment pack (front-loaded:
//                              latency-bound, overlaps the GEMM wavefront)
//             blocks [48,560): gx GEMM, tile 128(M) x 384(N), K=128.
// gx[t*B+b][n] = bf16( (x[b,t,:]@Wx[:,n] + bx[n] + (n<512?bh[n]:0)) * sc ),
// sc = L2E (r,z) / 2*L2E (n). 512 thr = 8 waves (2M x 4N); per wave
// 4m x 6n x 4k = 96 MFMA; LDS: A 34KB + B 96KB(+pad) = 139KB, C staged via
// LDS alias for 16B coalesced stores.
__global__ __launch_bounds__(512) void prep1(const float* __restrict__ x,
                                             const u16* __restrict__ WxT,
                                             const float* __restrict__ bx,
                                             const float* __restrict__ bh,
                                             const float* __restrict__ Wh,
                                             const float* __restrict__ sw,
                                             u16* __restrict__ gxw,
                                             signed char* __restrict__ whp8) {
  __shared__ __align__(16) char smem[(128 * 136 + 384 * 136) * 2];  // 139 KB
  const int bid = blockIdx.x;
  const int tid = threadIdx.x;

  if (bid < 48) {                               // ---- Wh int8 pack ----
    int o8 = bid * 512 + tid;                   // 0..24575 (8 bytes each)
    int j8 = o8 & 1;
    int kk = (o8 >> 1) & 3;
    int g  = (o8 >> 3) % 3;
    int tp = o8 / 24;                           // scan-kernel tid, 0..1023
    int l  = tp & 63, w = tp >> 6;
    int n  = g * 256 + w * 16 + (l & 15);
    int kbase = kk * 64 + ((l >> 4) & 3) * 16 + j8 * 8;
    float rs = rcp_(sw[n]);                     // 127 / max_k|Wh[:,n]|
    c8x8 v;
    #pragma unroll
    for (int j = 0; j < 8; ++j) {
      float q = __builtin_rintf(Wh[(size_t)(kbase + j) * H3_ + n] * rs);
      v[j] = (signed char)(int)q;
    }
    *(c8x8*)(whp8 + (size_t)o8 * 8) = v;
    return;
  }

  // ---- gx GEMM ----
  u16 (*As)[136] = (u16(*)[136])smem;
  u16 (*Bs)[136] = (u16(*)[136])(smem + 128 * 136 * 2);
  u16 (*St)[392] = (u16(*)[392])smem;           // aliases after 2nd barrier

  const int gb = bid - 48;                      // 0..511
  const int mt = gb & 255;
  const int n0 = (gb >> 8) * 384;               // 0 or 384
  const int m0 = mt * 128;
  const int t  = mt >> 1;
  const int brow0 = (mt & 1) * 128;
  const int w = tid >> 6, lane = tid & 63, quad = lane >> 4, r = lane & 15;
  const int wm = w >> 2, wn = w & 3;            // 2 x 4 wave grid

  {  // A tile: 128 rows x 128 cols, f32 -> bf16; 4-lane groups read 64B
    int row = tid >> 2;
    int colc = (tid & 3) * 4;
    const float* s = x + ((size_t)(brow0 + row) * T_ + t) * IN_ + colc;
    #pragma unroll
    for (int c4 = 0; c4 < 8; ++c4) {
      f32x4 v = *(const f32x4*)(s + c4 * 16);
      u16x4 b;
      b[0] = f2bf(v[0]); b[1] = f2bf(v[1]); b[2] = f2bf(v[2]); b[3] = f2bf(v[3]);
      *(u16x4*)&As[row][colc + c4 * 16] = b;
    }
  }
  {  // B tile [n][k] from WxT: 384 x 128 u16
    #pragma unroll
    for (int i = 0; i < 12; ++i) {
      int idx = tid + i * 512;                  // 0..6143
      int row = idx >> 4, col8 = (idx & 15) * 8;
      *(u16x8*)&Bs[row][col8] = *(const u16x8*)(WxT + (size_t)(n0 + row) * IN_ + col8);
    }
  }
  __syncthreads();

  f32x4 acc[4][6];
  #pragma unroll
  for (int i = 0; i < 4; ++i)
    #pragma unroll
    for (int j = 0; j < 6; ++j)
      acc[i][j] = (f32x4){0.f, 0.f, 0.f, 0.f};

  #pragma unroll
  for (int kk = 0; kk < 4; ++kk) {
    bf16x8 a[4];
    #pragma unroll
    for (int m2 = 0; m2 < 4; ++m2)
      a[m2] = *(const bf16x8*)&As[wm * 64 + m2 * 16 + r][kk * 32 + quad * 8];
    #pragma unroll
    for (int n2 = 0; n2 < 6; ++n2) {
      bf16x8 b = *(const bf16x8*)&Bs[wn * 96 + n2 * 16 + r][kk * 32 + quad * 8];
      #pragma unroll
      for (int m2 = 0; m2 < 4; ++m2)
        acc[m2][n2] = mfma16(a[m2], b, acc[m2][n2]);
    }
  }

  __syncthreads();   // all LDS reads done; safe to alias As/Bs as St

  #pragma unroll
  for (int m2 = 0; m2 < 4; ++m2)
    #pragma unroll
    for (int n2 = 0; n2 < 6; ++n2) {
      int nl = wn * 96 + n2 * 16 + r;           // local col (C col = lane&15)
      int n  = n0 + nl;
      float sc = (n < 512) ? L2E : (2.f * L2E);
      float bias = bx[n] + (n < 512 ? bh[n] : 0.f);
      #pragma unroll
      for (int e = 0; e < 4; ++e) {             // C row = quad*4 + e
        int mrow = wm * 64 + m2 * 16 + quad * 4 + e;
        St[mrow][nl] = f2bf((acc[m2][n2][e] + bias) * sc);
      }
    }
  __syncthreads();

  #pragma unroll
  for (int i = 0; i < 12; ++i) {                // coalesced 16B stores
    int idx = tid + i * 512;                    // 0..6143
    int row = idx / 48, c8 = (idx % 48) * 8;
    *(u16x8*)(gxw + (size_t)(m0 + row) * H3_ + n0 + c8) = *(const u16x8*)&St[row][c8];
  }
}

// ---------------------------------------------------------------------------
// K3: the scan, INT8. 192 blocks x 1024 threads, 4 batch rows/block.
// Per step: 4 eager ds_read_b128 -> 12 MFMA kk-major (3-way ILP) ->
// unconditional gx(t+1) prefetch -> dequant epilogue -> ds_write_b8 ->
// one barrier. 48 VGPR frag file, no spill.
__global__ __launch_bounds__(1024)
void cru_scan(const float* __restrict__ hid,
              const signed char* __restrict__ whp8,
              const float* __restrict__ sw,
              const float* __restrict__ bh,
              const u16*  __restrict__ gx,
              float* __restrict__ hT) {
  __shared__ __align__(16) signed char h8[2][4][288];   // double buffer, 2.3 KB

  const int bid = blockIdx.x;           // 192 blocks
  const int c   = bid >> 6;             // component 0..2
  const int b0  = (bid & 63) << 2;      // batch row group of 4
  const int tid = threadIdx.x;
  const int lane = tid & 63, quad = lane >> 4, m = lane & 15;
  const int w  = tid >> 6;              // wave 0..15
  const int bb = m & 3;                 // batch row within group
  const int e  = m >> 2;                // kept accumulator element
  const int hcol = w * 16 + quad * 4 + e;   // owned n-col 0..255

  // --- one-time fragment load: 192 B contiguous per thread, coalesced ---
  i32x4 bfr[3][4];
  {
    const signed char* wp = whp8 + (size_t)tid * 192;
    #pragma unroll
    for (int g = 0; g < 3; ++g)
      #pragma unroll
      for (int kk = 0; kk < 4; ++kk)
        bfr[g][kk] = *(const i32x4*)(wp + g * 64 + kk * 16);
  }

  // --- dequant constants: gh = acc * sW/127, then gate prescale ---
  const float dqR = sw[hcol]       * (L2E / 127.f);
  const float dqZ = sw[256 + hcol] * (L2E / 127.f);
  const float dqN = sw[512 + hcol] * (2.f * L2E / 127.f);

  // --- this lane's h element: h[bb][hcol] ---
  const size_t hrow = (size_t)(c * 256 + b0 + bb) * 256 + hcol;
  float hx = hid[hrow];
  h8[0][bb][hcol] = (signed char)(int)__builtin_rintf(fminf(fmaxf(hx, -1.f), 1.f) * 127.f);
  const float bn0 = bh[512 + hcol] * (2.f * L2E);

  const u16* gxp = gx + (size_t)(b0 + bb) * H3_ + hcol;
  const int rbase = bb * 288 + quad * 16;      // B-frag read base (bytes)

  // prefetch t=0 gx values
  u16 xr = gxp[0], xz = gxp[256], xn = gxp[512];
  const u16* gxs = gxp + (size_t)(B_ * H3_);   // points at t+1

  __syncthreads();

  #pragma unroll 2
  for (int t = 0; t < T_; ++t) {
    const int sel = t & 1;

    // A) eager B-frag reads (4 x ds_read_b128, 16 distinct addrs, 4-way
    //    same-address broadcast, 2-way bank aliasing = free)
    const signed char* hb = &h8[sel][0][0];
    i32x4 f0 = *(const i32x4*)(hb + rbase);
    i32x4 f1 = *(const i32x4*)(hb + rbase + 64);
    i32x4 f2 = *(const i32x4*)(hb + rbase + 128);
    i32x4 f3 = *(const i32x4*)(hb + rbase + 192);

    // B) kk-major MFMA: 3 independent accumulator chains interleaved
    __builtin_amdgcn_s_setprio(1);
    i32x4 accR = {0, 0, 0, 0};
    i32x4 accZ = {0, 0, 0, 0};
    i32x4 accN = {0, 0, 0, 0};
    accR = mfma8(bfr[0][0], f0, accR);
    accZ = mfma8(bfr[1][0], f0, accZ);
    accN = mfma8(bfr[2][0], f0, accN);
    accR = mfma8(bfr[0][1], f1, accR);
    accZ = mfma8(bfr[1][1], f1, accZ);
    accN = mfma8(bfr[2][1], f1, accN);
    accR = mfma8(bfr[0][2], f2, accR);
    accZ = mfma8(bfr[1][2], f2, accZ);
    accN = mfma8(bfr[2][2], f2, accN);
    accR = mfma8(bfr[0][3], f3, accR);
    accZ = mfma8(bfr[1][3], f3, accZ);
    accN = mfma8(bfr[2][3], f3, accN);
    __builtin_amdgcn_s_setprio(0);

    // C) unconditional gx(t+1) prefetch (t=127 reads land in mapped hTw
    //    region; values discarded)
    u16 nxr = gxs[0], nxz = gxs[256], nxn = gxs[512];
    gxs += B_ * H3_;

    // D) r/z sigmoids
    float gR = (float)pick4i(accR, e) * dqR;
    float gZ = (float)pick4i(accZ, e) * dqZ;
    float sr = rcp_(1.f + exp2f_(-(bf2f(xr) + gR)));       // sigmoid
    float sz = rcp_(1.f + exp2f_(-(bf2f(xz) + gZ)));

    // E) tanh + GRU update
    float gN = (float)pick4i(accN, e) * dqN;
    float nv = bf2f(xn) + sr * (gN + bn0);                 // 2*L2E-scaled
    float nn = fmaf(2.f, rcp_(1.f + exp2f_(-nv)), -1.f);   // tanh, inf-safe
    float hv = nn + sz * (hx - nn);
    hx = hv;
    h8[sel ^ 1][bb][hcol] = (signed char)(int)__builtin_rintf(hv * 127.f);
    xr = nxr; xz = nxz; xn = nxn;
    __syncthreads();   // h8[sel^1] ready; orders next-step reads of sel
  }

  hT[hrow] = hx;
}

// ---------------------------------------------------------------------------
// K4: out[b] = elu(sum_c hT[c,b,:] @ Wf + bf); feature[c,:] = mean_b hT
__global__ __launch_bounds__(128) void finalize(const float* __restrict__ hT,
                                                const float* __restrict__ Wf,
                                                const float* __restrict__ bfv,
                                                float* __restrict__ out) {
  __shared__ float hsum[256];
  const int bid = blockIdx.x, tid = threadIdx.x;
  if (bid < 256) {
    const int b = bid;
    for (int k = tid; k < 256; k += 128)
      hsum[k] = hT[((size_t)(0 * 256 + b)) * 256 + k]
              + hT[((size_t)(1 * 256 + b)) * 256 + k]
              + hT[((size_t)(2 * 256 + b)) * 256 + k];
    __syncthreads();
    float acc = bfv[tid];
    #pragma unroll 8
    for (int k = 0; k < 256; ++k)
      acc = fmaf(hsum[k], Wf[(size_t)k * OUT_ + tid], acc);
    float rv = acc > 0.f ? acc : (__expf(acc) - 1.f);
    out[b * OUT_ + tid] = rv;
  } else {
    const int idx = bid - 256;                 // 0..5
    const int c = idx >> 1, j = ((idx & 1) << 7) + tid;
    float sum = 0.f;
    #pragma unroll 4
    for (int b = 0; b < 256; ++b)
      sum += hT[((size_t)(c * 256 + b)) * 256 + j];
    out[B_ * OUT_ + c * 256 + j] = sum * (1.f / 256.f);
  }
}

// ---------------------------------------------------------------------------
extern "C" void kernel_launch(void* const* d_in, const int* in_sizes, int n_in,
                              void* d_out, int out_size, void* d_ws, size_t ws_size,
                              hipStream_t stream) {
  const float* x   = (const float*)d_in[0];
  const float* hid = (const float*)d_in[1];
  const float* Wx  = (const float*)d_in[2];
  const float* bx  = (const float*)d_in[3];
  const float* Wh  = (const float*)d_in[4];
  const float* bh  = (const float*)d_in[5];
  const float* Wf  = (const float*)d_in[6];
  const float* bf_ = (const float*)d_in[7];
  float* out = (float*)d_out;

  char* ws = (char*)d_ws;
  u16* WxT   = (u16*)ws;                                   // 768*128 bf16 = 192 KiB
  u16* gxw   = (u16*)(ws + (1 << 18));                     // 48 MiB
  size_t off = (1 << 18) + (size_t)T_ * B_ * H3_ * 2;
  float* hTw = (float*)(ws + off);                         // 3*256*256 f32 = 768 KiB
  off += (size_t)3 * 256 * 256 * 4;
  signed char* whp8 = (signed char*)(ws + off);            // 1024*192 = 192 KiB
  off += (size_t)1024 * 192;
  float* sww = (float*)(ws + off);                         // 768 f32

  prep0<<<108, 1024, 0, stream>>>(Wx, Wh, WxT, sww);
  prep1<<<560, 512, 0, stream>>>(x, WxT, bx, bh, Wh, sww, gxw, whp8);
  cru_scan<<<192, 1024, 0, stream>>>(hid, whp8, sww, bh, gxw, hTw);
  finalize<<<262, 128, 0, stream>>>(hTw, Wf, bf_, out);
}